// Round 2
// baseline (597.183 us; speedup 1.0000x reference)
//
#include <hip/hip_runtime.h>

#define NC     19      // n_coef
#define DIM    64      // INPUT_DIM
#define ODIM   64      // OUTPUT_DIM
#define NROWS  65536   // BATCH

// ws layout (bytes)
#define MM_OFF     0
#define COEFT_OFF  1024                     // 64*19*64 f32 = 311296 B
#define SILU_OFF   (COEFT_OFF + 311296)     // 65536 f32 = 262144 B

// grid value: G[0..2]={-1,-.875,-.75}, G[3..19]=-1+.125*(i-3), G[20..22]={.75,.875,1}
// (reference grid is NON-monotonic: concat(g[:3], g, g[-3:]) — gval maps faithfully)
__device__ __forceinline__ float gval(int i) {
    int j = (i < 3) ? i : (i < 20 ? i - 3 : i - 6);
    return -1.0f + 0.125f * (float)j;   // exact multiples of 0.125
}

__device__ __forceinline__ unsigned fenc(float f) {
    unsigned u = __float_as_uint(f);
    return (u & 0x80000000u) ? ~u : (u | 0x80000000u);
}
__device__ __forceinline__ float fdec(unsigned e) {
    unsigned u = (e & 0x80000000u) ? (e & 0x7fffffffu) : ~e;
    return __uint_as_float(u);
}

__global__ void kan_init(unsigned* mm) {
    mm[0] = 0xFFFFFFFFu;   // running-min (encoded), init = +max
    mm[1] = 0u;            // running-max (encoded), init = -max
}

__global__ __launch_bounds__(256) void kan_minmax(const float* __restrict__ x,
                                                  unsigned* __restrict__ mm) {
    const int n4 = (NROWS * DIM) / 4;
    int i0 = blockIdx.x * blockDim.x + threadIdx.x;
    float lmin = 3.0e38f, lmax = -3.0e38f;
    for (int i = i0; i < n4; i += gridDim.x * blockDim.x) {
        float4 v = reinterpret_cast<const float4*>(x)[i];
        lmin = fminf(lmin, fminf(fminf(v.x, v.y), fminf(v.z, v.w)));
        lmax = fmaxf(lmax, fmaxf(fmaxf(v.x, v.y), fmaxf(v.z, v.w)));
    }
    #pragma unroll
    for (int s = 32; s; s >>= 1) {
        lmin = fminf(lmin, __shfl_xor(lmin, s, 64));
        lmax = fmaxf(lmax, __shfl_xor(lmax, s, 64));
    }
    __shared__ float smn[4], smx[4];
    int wv = threadIdx.x >> 6;
    if ((threadIdx.x & 63) == 0) { smn[wv] = lmin; smx[wv] = lmax; }
    __syncthreads();
    if (threadIdx.x == 0) {
        float a = smn[0], b = smx[0];
        #pragma unroll
        for (int k = 1; k < 4; ++k) { a = fminf(a, smn[k]); b = fmaxf(b, smx[k]); }
        atomicMin(&mm[0], fenc(a));   // fp32 min/max exact -> order-independent
        atomicMax(&mm[1], fenc(b));
    }
}

// per-row sum of xn*sigmoid(xn) -> silu[row]
__global__ __launch_bounds__(256) void kan_silu(const float* __restrict__ x,
                                                const unsigned* __restrict__ mm,
                                                float* __restrict__ silu) {
    const int lane = threadIdx.x & 63;
    const int wv   = threadIdx.x >> 6;
    const float mn = fdec(mm[0]);
    const float mx = fdec(mm[1]);
    const float den = (mx - mn) + 1e-6f;
    const int base = blockIdx.x * 64 + wv * 16;
    for (int k = 0; k < 16; ++k) {
        const int row = base + k;
        float xv = x[(size_t)row * DIM + lane];
        float xn = ((xv - mn) / den) * 2.0f - 1.0f;
        xn = fminf(fmaxf(xn, -1.0f), 1.0f);
        float s = xn * (1.0f / (1.0f + expf(-xn)));
        #pragma unroll
        for (int sh = 32; sh; sh >>= 1) s += __shfl_xor(s, sh, 64);
        if (lane == 0) silu[row] = s;
    }
}

// coef [d][o][c] -> coefT [d][c][o]  (311 KB, one-time per call)
__global__ __launch_bounds__(256) void kan_tcoef(const float* __restrict__ coef,
                                                 float* __restrict__ coefT) {
    const int d = blockIdx.x;
    const float* src = coef + (size_t)d * (ODIM * NC);
    float* dst = coefT + (size_t)d * (NC * ODIM);
    for (int idx = threadIdx.x; idx < ODIM * NC; idx += 256) {
        int o = idx / NC;
        int c = idx - o * NC;
        dst[c * ODIM + o] = src[idx];
    }
}

// main: dense rows-in-lanes einsum. Wave = 64 rows (lane = row), acc[64 o] in VGPRs.
// coef delivered as wave-uniform LDS b128 broadcasts; basis dense vector in scratch.
__global__ __launch_bounds__(128) void kan_main(const float* __restrict__ x,
                                                const float* __restrict__ coefT,
                                                const float* __restrict__ wb,
                                                const float* __restrict__ wsp,
                                                const float* __restrict__ silu,
                                                float* __restrict__ out,
                                                const unsigned* __restrict__ mm) {
    __shared__ __align__(16) float  sCoefT[4 * NC * ODIM];  // [dq][c][o], 19456 B
    __shared__ __align__(16) float4 sTbl[60];               // lvl1[21] lvl2[20] lvl3[19]

    const int tid  = threadIdx.x;
    const int lane = tid & 63;
    const int wv   = tid >> 6;                 // 0..1
    const int row  = blockIdx.x * 128 + wv * 64 + lane;

    // recursion constant table: {G[i], 1/(G[i+K]-G[i]+1e-5), G[i+K+1], 1/(G[i+K+1]-G[i+1]+1e-5)}
    if (tid < 60) {
        int KK, i;
        if (tid < 21)      { KK = 1; i = tid; }
        else if (tid < 41) { KK = 2; i = tid - 21; }
        else               { KK = 3; i = tid - 41; }
        float gl  = gval(i);
        float gr  = gval(i + KK + 1);
        float ldn = gval(i + KK) - gl + 1e-5f;
        float rdn = gr - gval(i + 1) + 1e-5f;
        sTbl[tid] = make_float4(gl, 1.0f / ldn, gr, 1.0f / rdn);
    }

    const float mn  = fdec(mm[0]);
    const float mx  = fdec(mm[1]);
    const float den = (mx - mn) + 1e-6f;

    float acc[64];
    #pragma unroll
    for (int i = 0; i < 64; ++i) acc[i] = 0.0f;

    float bd[NC];                 // dense basis vector: runtime-indexed -> scratch (vmem pipe)
    #pragma unroll
    for (int c = 0; c < NC; ++c) bd[c] = 0.0f;

    const float* xrow = x + (size_t)row * DIM;

    for (int ch = 0; ch < 16; ++ch) {
        __syncthreads();   // previous chunk's sCoefT readers done
        // stage 4 d's of coefT: 19456 B = 19 linear 1 KiB wave-segments
        {
            const float* gsrc = coefT + (size_t)ch * (4 * NC * ODIM);
            for (int seg = wv; seg < 19; seg += 2) {
                __builtin_amdgcn_global_load_lds(
                    (const __attribute__((address_space(1))) void*)(gsrc + seg * 256 + lane * 4),
                    (__attribute__((address_space(3))) void*)(&sCoefT[seg * 256]),
                    16, 0, 0);
            }
        }
        // this chunk's 4 x-values for my row (16B-aligned dwordx4)
        const float4 xv4 = *reinterpret_cast<const float4*>(xrow + ch * 4);
        __syncthreads();   // barrier drains vmcnt -> sCoefT ready

        #pragma unroll
        for (int dq = 0; dq < 4; ++dq) {
            float xraw = (dq == 0) ? xv4.x : (dq == 1) ? xv4.y : (dq == 2) ? xv4.z : xv4.w;
            float xn = ((xraw - mn) / den) * 2.0f - 1.0f;
            xn = fminf(fmaxf(xn, -1.0f), 1.0f);

            // interval m with exact-comparison fixup
            int m = (int)((xn + 1.0f) * 8.0f);
            m = min(max(m, 0), 15);
            float knot = -1.0f + 0.125f * (float)m;
            if (xn < knot) m -= 1;
            else if (xn >= knot + 0.125f) m += 1;
            m = min(max(m, 0), 15);
            int w = min(max(m - 1, 0), 13);    // 6-wide window [w,w+5] covers all nonzeros

            // exact windowed Cox-de Boor over the true (non-monotonic) grid
            float4 e[8];
            #pragma unroll
            for (int j = 0; j < 8; ++j) e[j] = sTbl[w + j];
            float g9[10];
            #pragma unroll
            for (int j = 0; j < 8; ++j) g9[j] = e[j].x;
            g9[8] = e[6].z;                    // G[w+8]
            g9[9] = e[7].z;                    // G[w+9]

            float b0[9];
            #pragma unroll
            for (int j = 0; j < 9; ++j)
                b0[j] = (xn >= g9[j] && xn < g9[j + 1]) ? 1.0f : 0.0f;
            float b1[8];
            #pragma unroll
            for (int j = 0; j < 8; ++j)
                b1[j] = (xn - e[j].x) * e[j].y * b0[j] + (e[j].z - xn) * e[j].w * b0[j + 1];
            float b2[7];
            #pragma unroll
            for (int j = 0; j < 7; ++j) {
                float4 t = sTbl[21 + w + j];
                b2[j] = (xn - t.x) * t.y * b1[j] + (t.z - xn) * t.w * b1[j + 1];
            }
            float b3[6];
            #pragma unroll
            for (int j = 0; j < 6; ++j) {
                float4 t = sTbl[41 + w + j];
                b3[j] = (xn - t.x) * t.y * b2[j] + (t.z - xn) * t.w * b2[j + 1];
            }

            #pragma unroll
            for (int j = 0; j < 6; ++j) bd[w + j] = b3[j];   // scatter into pre-zeroed dense vec

            // dense einsum: for each c, wave-uniform b128 coef broadcasts feed 64 o-FMAs
            const float* cbase = &sCoefT[dq * (NC * ODIM)];
            for (int c = 0; c < NC; ++c) {
                const float bc = bd[c];
                const float4* cp = reinterpret_cast<const float4*>(cbase + c * ODIM);
                #pragma unroll
                for (int og = 0; og < 16; ++og) {
                    float4 cv = cp[og];          // uniform addr -> LDS broadcast
                    acc[og * 4 + 0] = fmaf(bc, cv.x, acc[og * 4 + 0]);
                    acc[og * 4 + 1] = fmaf(bc, cv.y, acc[og * 4 + 1]);
                    acc[og * 4 + 2] = fmaf(bc, cv.z, acc[og * 4 + 2]);
                    acc[og * 4 + 3] = fmaf(bc, cv.w, acc[og * 4 + 3]);
                }
            }

            #pragma unroll
            for (int j = 0; j < 6; ++j) bd[w + j] = 0.0f;    // restore zeros for next d
        }
    }

    // epilogue: out[row][o] = wb[o]*silu_sum[row] + ws[o]*spline
    const float sl = silu[row];
    float* orow = out + (size_t)row * ODIM;
    #pragma unroll
    for (int og = 0; og < 16; ++og) {
        float4 wbv = *reinterpret_cast<const float4*>(wb + og * 4);
        float4 wsv = *reinterpret_cast<const float4*>(wsp + og * 4);
        float4 o4;
        o4.x = wbv.x * sl + wsv.x * acc[og * 4 + 0];
        o4.y = wbv.y * sl + wsv.y * acc[og * 4 + 1];
        o4.z = wbv.z * sl + wsv.z * acc[og * 4 + 2];
        o4.w = wbv.w * sl + wsv.w * acc[og * 4 + 3];
        reinterpret_cast<float4*>(orow)[og] = o4;
    }
}

extern "C" void kernel_launch(void* const* d_in, const int* in_sizes, int n_in,
                              void* d_out, int out_size, void* d_ws, size_t ws_size,
                              hipStream_t stream) {
    const float* x    = (const float*)d_in[0];
    const float* coef = (const float*)d_in[1];
    const float* wb   = (const float*)d_in[2];
    const float* wsp  = (const float*)d_in[3];
    float* outp       = (float*)d_out;

    char* ws = (char*)d_ws;
    unsigned* mm  = (unsigned*)(ws + MM_OFF);
    float* coefT  = (float*)(ws + COEFT_OFF);
    float* siluv  = (float*)(ws + SILU_OFF);

    kan_init  <<<1,    1,   0, stream>>>(mm);
    kan_minmax<<<2048, 256, 0, stream>>>(x, mm);
    kan_silu  <<<1024, 256, 0, stream>>>(x, mm, siluv);
    kan_tcoef <<<64,   256, 0, stream>>>(coef, coefT);
    kan_main  <<<512,  128, 0, stream>>>(x, coefT, wb, wsp, siluv, outp, mm);
}

// Round 3
// 208.159 us; speedup vs baseline: 2.8689x; 2.8689x over previous
//
#include <hip/hip_runtime.h>

typedef __attribute__((ext_vector_type(8))) short short8;
typedef __attribute__((ext_vector_type(4))) float f32x4;

#define NC     19
#define DIM    64
#define ODIM   64
#define NROWS  65536
#define CPAD   24                    // c padded 19->24 (multiples of 8)
#define DCH    4                     // d's per chunk
#define NCHUNK (DIM / DCH)           // 16
#define KSC    3                     // 32-wide ksteps per chunk (4*24/32)

// ws layout (bytes)
#define MM_OFF  0
#define BPLANE  (NCHUNK * KSC * 4 * 64 * 16)   // 196608 B per bf16 plane
#define BH_OFF  1024
#define BL_OFF  (BH_OFF + BPLANE)

// reference grid: concat(g[:3], g, g[-3:]), g = linspace(-1,1,17) — NON-monotonic, mapped faithfully
__host__ __device__ constexpr float Gc(int i) {
    int j = (i < 3) ? i : (i < 20 ? i - 3 : i - 6);
    return -1.0f + 0.125f * (float)j;          // exact multiples of 0.125
}
__host__ __device__ constexpr float invLd(int KK, int j) { return 1.0f / (Gc(j + KK) - Gc(j) + 1e-5f); }
__host__ __device__ constexpr float invRd(int KK, int j) { return 1.0f / (Gc(j + KK + 1) - Gc(j + 1) + 1e-5f); }

__device__ __forceinline__ unsigned short bf16_rne(float f) {
    unsigned u = __float_as_uint(f);
    unsigned r = u + 0x7FFFu + ((u >> 16) & 1u);
    return (unsigned short)(r >> 16);
}
__device__ __forceinline__ float bf16_tof(unsigned short h) {
    return __uint_as_float(((unsigned)h) << 16);
}

__device__ __forceinline__ unsigned fenc(float f) {
    unsigned u = __float_as_uint(f);
    return (u & 0x80000000u) ? ~u : (u | 0x80000000u);
}
__device__ __forceinline__ float fdec(unsigned e) {
    unsigned u = (e & 0x80000000u) ? (e & 0x7fffffffu) : ~e;
    return __uint_as_float(u);
}

// dense-static Cox-de Boor, literal constants, all-static indexing (registers only)
__device__ __forceinline__ void dense_basis(float x, float* b3) {
    float b0[22];
    #pragma unroll
    for (int j = 0; j < 22; ++j)
        b0[j] = (x >= Gc(j) && x < Gc(j + 1)) ? 1.0f : 0.0f;
    float b1[21];
    #pragma unroll
    for (int j = 0; j < 21; ++j)
        b1[j] = (x - Gc(j)) * invLd(1, j) * b0[j] + (Gc(j + 2) - x) * invRd(1, j) * b0[j + 1];
    float b2[20];
    #pragma unroll
    for (int j = 0; j < 20; ++j)
        b2[j] = (x - Gc(j)) * invLd(2, j) * b1[j] + (Gc(j + 3) - x) * invRd(2, j) * b1[j + 1];
    #pragma unroll
    for (int j = 0; j < 19; ++j)
        b3[j] = (x - Gc(j)) * invLd(3, j) * b2[j] + (Gc(j + 4) - x) * invRd(3, j) * b2[j + 1];
}

__global__ void kan_init(unsigned* mm) {
    mm[0] = 0xFFFFFFFFu;
    mm[1] = 0u;
}

__global__ __launch_bounds__(256) void kan_minmax(const float* __restrict__ x,
                                                  unsigned* __restrict__ mm) {
    const int n4 = (NROWS * DIM) / 4;
    int i0 = blockIdx.x * blockDim.x + threadIdx.x;
    float lmin = 3.0e38f, lmax = -3.0e38f;
    for (int i = i0; i < n4; i += gridDim.x * blockDim.x) {
        float4 v = reinterpret_cast<const float4*>(x)[i];
        lmin = fminf(lmin, fminf(fminf(v.x, v.y), fminf(v.z, v.w)));
        lmax = fmaxf(lmax, fmaxf(fmaxf(v.x, v.y), fmaxf(v.z, v.w)));
    }
    #pragma unroll
    for (int s = 32; s; s >>= 1) {
        lmin = fminf(lmin, __shfl_xor(lmin, s, 64));
        lmax = fmaxf(lmax, __shfl_xor(lmax, s, 64));
    }
    __shared__ float smn[4], smx[4];
    int wv = threadIdx.x >> 6;
    if ((threadIdx.x & 63) == 0) { smn[wv] = lmin; smx[wv] = lmax; }
    __syncthreads();
    if (threadIdx.x == 0) {
        float a = smn[0], b = smx[0];
        #pragma unroll
        for (int k = 1; k < 4; ++k) { a = fminf(a, smn[k]); b = fmaxf(b, smx[k]); }
        atomicMin(&mm[0], fenc(a));
        atomicMax(&mm[1], fenc(b));
    }
}

// pre-fragment coef into MFMA B-layout, bf16 hi/lo planes.
// vec index v = ((ch*3 + ksl)*4 + nf)*64 + lane; element i: k = ch*96+ksl*32+(lane>>4)*8+i,
// B[k][o] with k = d*24+c (c>=19 -> 0), o = nf*16 + (lane&15).
__global__ __launch_bounds__(256) void kan_tcoef(const float* __restrict__ coef,
                                                 short8* __restrict__ wsBh,
                                                 short8* __restrict__ wsBl) {
    int v = blockIdx.x * 256 + threadIdx.x;          // 12288 vectors
    int ch = v / 768, rem = v - ch * 768;
    int ksl = rem >> 8, rem2 = rem & 255;
    int nf = rem2 >> 6, l = rem2 & 63;
    int o = nf * 16 + (l & 15);
    short8 vh, vl;
    #pragma unroll
    for (int i = 0; i < 8; ++i) {
        int k = ch * 96 + ksl * 32 + (l >> 4) * 8 + i;
        int d = k / CPAD, c = k - d * CPAD;
        float val = (c < NC) ? coef[((size_t)d * ODIM + o) * NC + c] : 0.0f;
        unsigned short hb = bf16_rne(val);
        float lof = val - bf16_tof(hb);
        vh[i] = (short)hb;
        vl[i] = (short)bf16_rne(lof);
    }
    wsBh[v] = vh;
    wsBl[v] = vl;
}

// main: 64 rows/block, 4 waves; wave w = 16-row m-frag. Dense-static basis -> pre-fragmented
// LDS A (hi/lo); B staged from ws via global_load_lds; 12 MFMA per kstep (3-pass split, 4 n-frags).
__global__ __launch_bounds__(256, 3) void kan_main(const float* __restrict__ x,
                                                   const char* __restrict__ wsB,
                                                   const float* __restrict__ wb,
                                                   const float* __restrict__ wsp,
                                                   float* __restrict__ out,
                                                   const unsigned* __restrict__ mm) {
    // A slots padded *17 so producer-write banks spread evenly
    __shared__ short8 sAh[4 * KSC * 4 * 17];   // [m][ksl][kg][r16(17)] = 816 vecs
    __shared__ short8 sAl[4 * KSC * 4 * 17];
    __shared__ short8 sBh[KSC * 4 * 64];       // [ksl][nf][lane] = 768 vecs
    __shared__ short8 sBl[KSC * 4 * 64];
    __shared__ float  sSilu[64];

    const int tid = threadIdx.x;
    const int l   = tid & 63;
    const int w   = tid >> 6;
    const int n0  = blockIdx.x * 64;

    const float mn  = fdec(mm[0]);
    const float mx  = fdec(mm[1]);
    const float den = (mx - mn) + 1e-6f;
    const float inv = 1.0f / den;

    // prologue: fused silu row-sums (wave-local: wave w covers its own 16 rows)
    {
        int r16 = l >> 2, q = l & 3;
        int row = n0 + w * 16 + r16;
        const float4* xr = reinterpret_cast<const float4*>(x + (size_t)row * DIM + q * 16);
        float s = 0.0f;
        #pragma unroll
        for (int j = 0; j < 4; ++j) {
            float4 v = xr[j];
            #pragma unroll
            for (int e = 0; e < 4; ++e) {
                float xv = (e == 0) ? v.x : (e == 1) ? v.y : (e == 2) ? v.z : v.w;
                float xn = ((xv - mn) * inv) * 2.0f - 1.0f;
                xn = fminf(fmaxf(xn, -1.0f), 1.0f);
                s += xn * (1.0f / (1.0f + expf(-xn)));
            }
        }
        s += __shfl_xor(s, 1);
        s += __shfl_xor(s, 2);
        if (q == 0) sSilu[w * 16 + r16] = s;
    }

    f32x4 acc[4];
    #pragma unroll
    for (int nf = 0; nf < 4; ++nf) acc[nf] = (f32x4){0.0f, 0.0f, 0.0f, 0.0f};

    const char* pBh = wsB + BH_OFF - BH_OFF;   // wsB already points at BH plane base
    const char* pBl = wsB + BPLANE;

    for (int ch = 0; ch < NCHUNK; ++ch) {
        __syncthreads();   // previous chunk's consumers done

        // stage B chunk (async direct-to-LDS), 12 KiB/plane, 3 segs/wave/plane
        #pragma unroll
        for (int j = 0; j < 3; ++j) {
            int seg = w * 3 + j;
            __builtin_amdgcn_global_load_lds(
                (const __attribute__((address_space(1))) void*)(pBh + (size_t)ch * 12288 + seg * 1024 + l * 16),
                (__attribute__((address_space(3))) void*)((char*)sBh + seg * 1024), 16, 0, 0);
            __builtin_amdgcn_global_load_lds(
                (const __attribute__((address_space(1))) void*)(pBl + (size_t)ch * 12288 + seg * 1024 + l * 16),
                (__attribute__((address_space(3))) void*)((char*)sBl + seg * 1024), 16, 0, 0);
        }

        // producer: thread -> (row = w*16 + l>>2, d = ch*4 + (l&3)); dense basis -> frag-ordered A
        {
            int r16 = l >> 2;
            int dloc = l & 3;
            int row = n0 + w * 16 + r16;
            float xv = x[(size_t)row * DIM + ch * DCH + dloc];
            float xn = ((xv - mn) * inv) * 2.0f - 1.0f;
            xn = fminf(fmaxf(xn, -1.0f), 1.0f);
            float b3[NC];
            dense_basis(xn, b3);
            #pragma unroll
            for (int cg = 0; cg < 3; ++cg) {
                short8 vh, vl;
                #pragma unroll
                for (int i = 0; i < 8; ++i) {
                    int c = cg * 8 + i;
                    float bv = (c < NC) ? b3[c] : 0.0f;
                    unsigned short hb = bf16_rne(bv);
                    float lof = bv - bf16_tof(hb);
                    vh[i] = (short)hb;
                    vl[i] = (short)bf16_rne(lof);
                }
                int k0 = dloc * CPAD + cg * 8;           // 0..88, multiple of 8
                int ksl = k0 >> 5, kg = (k0 & 31) >> 3;
                int slot = ((w * KSC + ksl) * 4 + kg) * 17 + r16;
                sAh[slot] = vh;
                sAl[slot] = vl;
            }
        }

        __syncthreads();   // drains vmcnt (B staged) + LDS writes (A ready)

        // consumer: 3 ksteps x 4 n-frags x 3 passes
        const int kgc = l >> 4, r16c = l & 15;
        #pragma unroll
        for (int ks = 0; ks < KSC; ++ks) {
            int aslot = ((w * KSC + ks) * 4 + kgc) * 17 + r16c;
            short8 ah = sAh[aslot];
            short8 al = sAl[aslot];
            #pragma unroll
            for (int nf = 0; nf < 4; ++nf) {
                short8 bh = sBh[(ks * 4 + nf) * 64 + l];
                short8 bl = sBl[(ks * 4 + nf) * 64 + l];
                acc[nf] = __builtin_amdgcn_mfma_f32_16x16x32_bf16(ah, bh, acc[nf], 0, 0, 0);
                acc[nf] = __builtin_amdgcn_mfma_f32_16x16x32_bf16(al, bh, acc[nf], 0, 0, 0);
                acc[nf] = __builtin_amdgcn_mfma_f32_16x16x32_bf16(ah, bl, acc[nf], 0, 0, 0);
            }
        }
    }

    // epilogue: D[row=(l>>4)*4+v][col=l&15] (m89 layout); out = wb*silu + ws*spline
    #pragma unroll
    for (int nf = 0; nf < 4; ++nf) {
        int o = nf * 16 + (l & 15);
        float wbv = wb[o];
        float wsv = wsp[o];
        #pragma unroll
        for (int v = 0; v < 4; ++v) {
            int rloc = (l >> 4) * 4 + v;
            int row = n0 + w * 16 + rloc;
            out[(size_t)row * ODIM + o] = wbv * sSilu[w * 16 + rloc] + wsv * acc[nf][v];
        }
    }
}

extern "C" void kernel_launch(void* const* d_in, const int* in_sizes, int n_in,
                              void* d_out, int out_size, void* d_ws, size_t ws_size,
                              hipStream_t stream) {
    const float* x    = (const float*)d_in[0];
    const float* coef = (const float*)d_in[1];
    const float* wb   = (const float*)d_in[2];
    const float* wsp  = (const float*)d_in[3];
    float* outp       = (float*)d_out;

    char* ws = (char*)d_ws;
    unsigned* mm  = (unsigned*)(ws + MM_OFF);
    short8* wsBh  = (short8*)(ws + BH_OFF);
    short8* wsBl  = (short8*)(ws + BL_OFF);

    kan_init  <<<1,    1,   0, stream>>>(mm);
    kan_minmax<<<2048, 256, 0, stream>>>(x, mm);
    kan_tcoef <<<48,   256, 0, stream>>>(coef, wsBh, wsBl);
    kan_main  <<<NROWS / 64, 256, 0, stream>>>(x, (const char*)(ws + BH_OFF), wb, wsp, outp, mm);
}

// Round 4
// 189.411 us; speedup vs baseline: 3.1528x; 1.0990x over previous
//
#include <hip/hip_runtime.h>

typedef __attribute__((ext_vector_type(8))) short short8;
typedef __attribute__((ext_vector_type(4))) float f32x4;

#define NC     19
#define CPAD   24
#define DIM    64
#define ODIM   64
#define NROWS  65536

// ws layout (bytes)
#define MM_OFF 0
#define T_OFF  64                    // 96 float4 = 1536 B
#define B_OFF  2048                  // bh plane then bl plane
#define BPLANE (16 * 3 * 4 * 64 * 16)   // 196608 B

// reference grid: concat(g[:3], g, g[-3:]), g = linspace(-1,1,17) — NON-monotonic, mapped faithfully
__host__ __device__ constexpr float Gc(int i) {
    int j = (i < 3) ? i : (i < 20 ? i - 3 : i - 6);
    return -1.0f + 0.125f * (float)j;     // exact multiples of 0.125
}

__device__ __forceinline__ unsigned short bf16_rne(float f) {
    unsigned u = __float_as_uint(f);
    unsigned r = u + 0x7FFFu + ((u >> 16) & 1u);
    return (unsigned short)(r >> 16);
}
__device__ __forceinline__ float bf16_tof(unsigned short h) {
    return __uint_as_float(((unsigned)h) << 16);
}
__device__ __forceinline__ unsigned fenc(float f) {
    unsigned u = __float_as_uint(f);
    return (u & 0x80000000u) ? ~u : (u | 0x80000000u);
}
__device__ __forceinline__ float fdec(unsigned e) {
    unsigned u = (e & 0x80000000u) ? (e & 0x7fffffffu) : ~e;
    return __uint_as_float(u);
}

// f64 port of the reference recursion (denominators rounded in f32 like the reference)
__device__ void dense_basis_f64(double x, double* b3) {
    double b0[22];
    #pragma unroll
    for (int j = 0; j < 22; ++j)
        b0[j] = (x >= (double)Gc(j) && x < (double)Gc(j + 1)) ? 1.0 : 0.0;
    double b1[21];
    #pragma unroll
    for (int j = 0; j < 21; ++j) {
        float dl = (Gc(j + 1) - Gc(j)) + 1e-5f;
        float dr = (Gc(j + 2) - Gc(j + 1)) + 1e-5f;
        b1[j] = (x - (double)Gc(j)) / (double)dl * b0[j] + ((double)Gc(j + 2) - x) / (double)dr * b0[j + 1];
    }
    double b2[20];
    #pragma unroll
    for (int j = 0; j < 20; ++j) {
        float dl = (Gc(j + 2) - Gc(j)) + 1e-5f;
        float dr = (Gc(j + 3) - Gc(j + 1)) + 1e-5f;
        b2[j] = (x - (double)Gc(j)) / (double)dl * b1[j] + ((double)Gc(j + 3) - x) / (double)dr * b1[j + 1];
    }
    #pragma unroll
    for (int j = 0; j < 19; ++j) {
        float dl = (Gc(j + 3) - Gc(j)) + 1e-5f;
        float dr = (Gc(j + 4) - Gc(j + 1)) + 1e-5f;
        b3[j] = (x - (double)Gc(j)) / (double)dl * b2[j] + ((double)Gc(j + 4) - x) / (double)dr * b2[j + 1];
    }
}

// blocks 0-47: coef -> MFMA-B-fragment bf16 hi/lo planes.  block 48: min/max init + poly-table fit.
__global__ __launch_bounds__(256) void kan_prep(const float* __restrict__ coef,
                                                short8* __restrict__ wsBh,
                                                short8* __restrict__ wsBl,
                                                float4* __restrict__ wsT,
                                                unsigned* __restrict__ mm) {
    const int tid = threadIdx.x;
    if (blockIdx.x < 48) {
        int v = blockIdx.x * 256 + tid;              // 12288 vectors
        int ch = v / 768, rem = v - ch * 768;
        int ksl = rem >> 8, rem2 = rem & 255;
        int nf = rem2 >> 6, l = rem2 & 63;
        int o = nf * 16 + (l & 15);
        short8 vh, vl;
        #pragma unroll
        for (int i = 0; i < 8; ++i) {
            int k = ch * 96 + ksl * 32 + (l >> 4) * 8 + i;
            int d = k / CPAD, c = k - d * CPAD;
            float val = (c < NC) ? coef[((size_t)d * ODIM + o) * NC + c] : 0.0f;
            unsigned short hb = bf16_rne(val);
            float lof = val - bf16_tof(hb);
            vh[i] = (short)hb;
            vl[i] = (short)bf16_rne(lof);
        }
        wsBh[v] = vh;
        wsBl[v] = vl;
    } else {
        if (tid == 0) { mm[0] = 0xFFFFFFFFu; mm[1] = 0u; }
        if (tid < 96) {
            int m = tid / 6, j = tid % 6;
            int w0 = min(max(m - 1, 0), 13);
            double knot = -1.0 + 0.125 * (double)m;
            const double S[4] = {0.125, 0.375, 0.625, 0.875};
            double y[4];
            #pragma unroll
            for (int i = 0; i < 4; ++i) {
                double b3[19];
                dense_basis_f64(knot + 0.125 * S[i], b3);
                y[i] = b3[w0 + j];
            }
            // divided differences -> monomial coefs (exact cubic => exact fit)
            double d01 = (y[1] - y[0]) / (S[1] - S[0]);
            double d12 = (y[2] - y[1]) / (S[2] - S[1]);
            double d23 = (y[3] - y[2]) / (S[3] - S[2]);
            double d012 = (d12 - d01) / (S[2] - S[0]);
            double d123 = (d23 - d12) / (S[3] - S[1]);
            double d0123 = (d123 - d012) / (S[3] - S[0]);
            double a3 = d0123;
            double a2 = d012 - d0123 * (S[0] + S[1] + S[2]);
            double a1 = d01 - d012 * (S[0] + S[1]) + d0123 * (S[0]*S[1] + S[0]*S[2] + S[1]*S[2]);
            double a0 = y[0] - d01 * S[0] + d012 * S[0]*S[1] - d0123 * S[0]*S[1]*S[2];
            wsT[tid] = make_float4((float)a0, (float)a1, (float)a2, (float)a3);
        }
    }
}

__global__ __launch_bounds__(256) void kan_minmax(const float* __restrict__ x,
                                                  unsigned* __restrict__ mm) {
    const int n4 = (NROWS * DIM) / 4;
    int i0 = blockIdx.x * blockDim.x + threadIdx.x;
    float lmin = 3.0e38f, lmax = -3.0e38f;
    for (int i = i0; i < n4; i += gridDim.x * blockDim.x) {
        float4 v = reinterpret_cast<const float4*>(x)[i];
        lmin = fminf(lmin, fminf(fminf(v.x, v.y), fminf(v.z, v.w)));
        lmax = fmaxf(lmax, fmaxf(fmaxf(v.x, v.y), fmaxf(v.z, v.w)));
    }
    #pragma unroll
    for (int s = 32; s; s >>= 1) {
        lmin = fminf(lmin, __shfl_xor(lmin, s, 64));
        lmax = fmaxf(lmax, __shfl_xor(lmax, s, 64));
    }
    __shared__ float smn[4], smx[4];
    int wv = threadIdx.x >> 6;
    if ((threadIdx.x & 63) == 0) { smn[wv] = lmin; smx[wv] = lmax; }
    __syncthreads();
    if (threadIdx.x == 0) {
        float a = smn[0], b = smx[0];
        #pragma unroll
        for (int k = 1; k < 4; ++k) { a = fminf(a, smn[k]); b = fmaxf(b, smx[k]); }
        atomicMin(&mm[0], fenc(a));
        atomicMax(&mm[1], fenc(b));
    }
}

// main: 4 waves x 32 rows = 128 rows/block. Wave-local A (no barriers in the K loop);
// B-frags straight from global (L2-resident). 2 m-frags per wave, 3-pass bf16 split MFMA.
__global__ __launch_bounds__(256, 3) void kan_main(const float* __restrict__ x,
                                                   const short8* __restrict__ wsBh,
                                                   const short8* __restrict__ wsBl,
                                                   const float4* __restrict__ wsT,
                                                   const float* __restrict__ wb,
                                                   const float* __restrict__ wsp,
                                                   float* __restrict__ out,
                                                   const unsigned* __restrict__ mm) {
    // per (wave,mf) A region: [ks(3)][kg(4)][r16 slots(17)] short8, hi+lo planes
    __shared__ short8 sAh[8 * 204];      // 26112 B
    __shared__ short8 sAl[8 * 204];      // 26112 B
    __shared__ float4 sT[96];            // 1536 B
    __shared__ float  sSilu[128];        // 512 B    -> 54272 B total, 3 blocks/CU

    const int tid = threadIdx.x;
    const int l   = tid & 63;
    const int w   = tid >> 6;
    const int n0  = blockIdx.x * 128;

    if (tid < 96) sT[tid] = wsT[tid];

    const float mn  = fdec(mm[0]);
    const float mx  = fdec(mm[1]);
    const float inv = 1.0f / ((mx - mn) + 1e-6f);

    // fused silu row-sums (wave-local)
    #pragma unroll
    for (int mf = 0; mf < 2; ++mf) {
        int r16 = l >> 2, q = l & 3;
        int row = n0 + w * 32 + mf * 16 + r16;
        const float4* xr = reinterpret_cast<const float4*>(x + (size_t)row * DIM + q * 16);
        float s = 0.0f;
        #pragma unroll
        for (int jj = 0; jj < 4; ++jj) {
            float4 v = xr[jj];
            #pragma unroll
            for (int e = 0; e < 4; ++e) {
                float xv = (e == 0) ? v.x : (e == 1) ? v.y : (e == 2) ? v.z : v.w;
                float xn = ((xv - mn) * inv) * 2.0f - 1.0f;
                xn = fminf(fmaxf(xn, -1.0f), 1.0f);
                s += xn * (1.0f / (1.0f + expf(-xn)));
            }
        }
        s += __shfl_xor(s, 1);
        s += __shfl_xor(s, 2);
        if (q == 0) sSilu[w * 32 + mf * 16 + r16] = s;
    }
    __syncthreads();   // sT visible to all waves (only barrier in the kernel)

    f32x4 acc[2][4];
    #pragma unroll
    for (int mf = 0; mf < 2; ++mf)
        #pragma unroll
        for (int nf = 0; nf < 4; ++nf) acc[mf][nf] = (f32x4){0.0f, 0.0f, 0.0f, 0.0f};

    unsigned* sAhw = (unsigned*)sAh;
    unsigned* sAlw = (unsigned*)sAl;
    const int r16 = l >> 2, dloc = l & 3;
    const int kgc = l >> 4, r16c = l & 15;

    for (int ch = 0; ch < 16; ++ch) {
        // ---- producer: windowed poly basis -> pre-fragmented wave-local A ----
        #pragma unroll
        for (int mf = 0; mf < 2; ++mf) {
            const int abase = (w * 2 + mf) * 204;
            int row = n0 + w * 32 + mf * 16 + r16;
            float xv = x[(size_t)row * DIM + ch * 4 + dloc];
            float xn = ((xv - mn) * inv) * 2.0f - 1.0f;
            xn = fminf(fmaxf(xn, -1.0f), 1.0f);

            int m = (int)((xn + 1.0f) * 8.0f);
            m = min(max(m, 0), 15);
            float knot = -1.0f + 0.125f * (float)m;
            if (xn < knot) m -= 1;
            else if (xn >= knot + 0.125f) m += 1;
            m = min(max(m, 0), 15);
            int w0 = min(max(m - 1, 0), 13);
            float s = (xn - (-1.0f + 0.125f * (float)m)) * 8.0f;   // s in [0,1)

            float b[6];
            #pragma unroll
            for (int j = 0; j < 6; ++j) {
                float4 T = sT[m * 6 + j];
                b[j] = ((T.w * s + T.z) * s + T.y) * s + T.x;
            }
            unsigned short hh[6];
            unsigned short hl[6];
            #pragma unroll
            for (int j = 0; j < 6; ++j) {
                hh[j] = bf16_rne(b[j]);
                hl[j] = bf16_rne(b[j] - bf16_tof(hh[j]));
            }
            // pair-aligned 8-wide window: c0 = w0 & ~1, shift e = w0 & 1
            const int e = w0 & 1;
            const int P0 = w0 >> 1;
            unsigned short vh[8], vl8[8];
            #pragma unroll
            for (int i = 0; i < 8; ++i) {
                unsigned short a = (i < 6) ? hh[i] : (unsigned short)0;        // e==0 pattern
                unsigned short bsh = (i >= 1 && i <= 6) ? hh[i - 1] : (unsigned short)0; // e==1
                vh[i] = e ? bsh : a;
                unsigned short c = (i < 6) ? hl[i] : (unsigned short)0;
                unsigned short dsh = (i >= 1 && i <= 6) ? hl[i - 1] : (unsigned short)0;
                vl8[i] = e ? dsh : c;
            }
            unsigned dwh[4], dwl[4];
            #pragma unroll
            for (int k = 0; k < 4; ++k) {
                dwh[k] = (unsigned)(unsigned short)vh[2 * k] | ((unsigned)(unsigned short)vh[2 * k + 1] << 16);
                dwl[k] = (unsigned)(unsigned short)vl8[2 * k] | ((unsigned)(unsigned short)vl8[2 * k + 1] << 16);
            }
            // zero this (row,d)'s 3 k-group vectors, both planes
            const short8 z8 = (short8){0, 0, 0, 0, 0, 0, 0, 0};
            #pragma unroll
            for (int gi = 0; gi < 3; ++gi) {
                int g = dloc * 3 + gi;
                int slot = abase + ((g >> 2) * 4 + (g & 3)) * 17 + r16;
                sAh[slot] = z8;
                sAl[slot] = z8;
            }
            // scatter the 4 window dwords, both planes
            #pragma unroll
            for (int pp = 0; pp < 4; ++pp) {
                int p = P0 + pp;                     // pair index 0..11 within this d
                int g = dloc * 3 + (p >> 2);
                int slot = abase + ((g >> 2) * 4 + (g & 3)) * 17 + r16;
                sAhw[slot * 4 + (p & 3)] = dwh[pp];
                sAlw[slot * 4 + (p & 3)] = dwl[pp];
            }
        }

        // ---- consumer: B from global (L2), A from wave-local LDS ----
        #pragma unroll
        for (int ks = 0; ks < 3; ++ks) {
            short8 bh[4], bl[4];
            #pragma unroll
            for (int nf = 0; nf < 4; ++nf) {
                int bv = ((ch * 3 + ks) * 4 + nf) * 64 + l;
                bh[nf] = wsBh[bv];
                bl[nf] = wsBl[bv];
            }
            #pragma unroll
            for (int mf = 0; mf < 2; ++mf) {
                int slotA = (w * 2 + mf) * 204 + (ks * 4 + kgc) * 17 + r16c;
                short8 ah = sAh[slotA];
                short8 al = sAl[slotA];
                #pragma unroll
                for (int nf = 0; nf < 4; ++nf) {
                    acc[mf][nf] = __builtin_amdgcn_mfma_f32_16x16x32_bf16(ah, bh[nf], acc[mf][nf], 0, 0, 0);
                    acc[mf][nf] = __builtin_amdgcn_mfma_f32_16x16x32_bf16(al, bh[nf], acc[mf][nf], 0, 0, 0);
                    acc[mf][nf] = __builtin_amdgcn_mfma_f32_16x16x32_bf16(ah, bl[nf], acc[mf][nf], 0, 0, 0);
                }
            }
        }
    }

    // epilogue: D[row=(l>>4)*4+v][col=l&15]; out = wb*silu + ws*spline
    #pragma unroll
    for (int nf = 0; nf < 4; ++nf) {
        int o = nf * 16 + (l & 15);
        float wbv = wb[o];
        float wsv = wsp[o];
        #pragma unroll
        for (int mf = 0; mf < 2; ++mf) {
            #pragma unroll
            for (int v = 0; v < 4; ++v) {
                int rloc = mf * 16 + (l >> 4) * 4 + v;
                int row = n0 + w * 32 + rloc;
                out[(size_t)row * ODIM + o] = wbv * sSilu[w * 32 + rloc] + wsv * acc[mf][nf][v];
            }
        }
    }
}

extern "C" void kernel_launch(void* const* d_in, const int* in_sizes, int n_in,
                              void* d_out, int out_size, void* d_ws, size_t ws_size,
                              hipStream_t stream) {
    const float* x    = (const float*)d_in[0];
    const float* coef = (const float*)d_in[1];
    const float* wb   = (const float*)d_in[2];
    const float* wsp  = (const float*)d_in[3];
    float* outp       = (float*)d_out;

    char* ws = (char*)d_ws;
    unsigned* mm  = (unsigned*)(ws + MM_OFF);
    float4*  wsT  = (float4*)(ws + T_OFF);
    short8*  wsBh = (short8*)(ws + B_OFF);
    short8*  wsBl = (short8*)(ws + B_OFF + BPLANE);

    kan_prep  <<<49,   256, 0, stream>>>(coef, wsBh, wsBl, wsT, mm);
    kan_minmax<<<2048, 256, 0, stream>>>(x, mm);
    kan_main  <<<NROWS / 128, 256, 0, stream>>>(x, wsBh, wsBl, wsT, wb, wsp, outp, mm);
}